// Round 1
// baseline (303.918 us; speedup 1.0000x reference)
//
#include <hip/hip_runtime.h>
#include <hip/hip_bf16.h>

#define NN 5000
#define NE 100000

__device__ __forceinline__ float silu_f(float x) {
    return x / (1.0f + __expf(-x));
}

// ---------------- x = nf @ W_pre * (1/sqrt(128)) ----------------
__global__ __launch_bounds__(128) void k_pre(const float* __restrict__ nf,
                                             const float* __restrict__ Wpre,
                                             float* __restrict__ x) {
    __shared__ float row[128];
    int n = blockIdx.x;
    int v = threadIdx.x;
    row[v] = nf[(size_t)n * 128 + v];
    __syncthreads();
    float acc = 0.f;
#pragma unroll 16
    for (int u = 0; u < 128; ++u) acc += row[u] * Wpre[u * 128 + v];
    x[(size_t)n * 128 + v] = acc * 0.08838834764831845f;
}

// ---------------- CSR build (int atomics only) ----------------
__global__ void k_count(const int* __restrict__ ei, int* __restrict__ counts) {
    int e = blockIdx.x * blockDim.x + threadIdx.x;
    if (e < NE) atomicAdd(&counts[ei[e]], 1);
}

__global__ __launch_bounds__(256) void k_scan(const int* __restrict__ counts,
                                              int* __restrict__ offsets) {
    __shared__ int part[256];
    int t = threadIdx.x;
    const int CH = 20;                 // 256*20 >= 5000
    int lo = t * CH, hi = min(lo + CH, NN);
    int s = 0;
    for (int i = lo; i < hi; ++i) s += counts[i];
    part[t] = s;
    __syncthreads();
    if (t == 0) {
        int run = 0;
        for (int i = 0; i < 256; ++i) { int v = part[i]; part[i] = run; run += v; }
    }
    __syncthreads();
    int run = part[t];
    for (int i = lo; i < hi; ++i) { offsets[i] = run; run += counts[i]; }
    if (t == 0) offsets[NN] = NE;
}

__global__ void k_fill(const int* __restrict__ ei, const int* __restrict__ offsets,
                       int* __restrict__ cursor, int* __restrict__ order) {
    int e = blockIdx.x * blockDim.x + threadIdx.x;
    if (e < NE) {
        int i = ei[e];
        int pos = atomicAdd(&cursor[i], 1);
        order[offsets[i] + pos] = e;
    }
}

// ---------------- batched edge MLP -> w_edge (bf16) ----------------
template<bool ACT>
__device__ __forceinline__ void mlp_layer64(const float (&src)[64][65], float (&dst)[64][65],
                                            const float* __restrict__ w, float scale,
                                            int ob, int mb) {
    float acc[4][4] = {};
    for (int k = 0; k < 64; ++k) {
        float wv[4];
#pragma unroll
        for (int c = 0; c < 4; ++c) wv[c] = w[k * 64 + ob + 16 * c];
#pragma unroll
        for (int mm = 0; mm < 4; ++mm) {
            float hv = src[mb + mm][k];
#pragma unroll
            for (int c = 0; c < 4; ++c) acc[mm][c] += hv * wv[c];
        }
    }
#pragma unroll
    for (int mm = 0; mm < 4; ++mm)
#pragma unroll
        for (int c = 0; c < 4; ++c) {
            float v = acc[mm][c] * scale;
            dst[mb + mm][ob + 16 * c] = ACT ? silu_f(v) : v;
        }
}

__global__ __launch_bounds__(256) void k_mlp(const float* __restrict__ rb,
                                             const float* __restrict__ w0,
                                             const float* __restrict__ w1,
                                             const float* __restrict__ w2,
                                             const float* __restrict__ w3,
                                             __hip_bfloat16* __restrict__ we) {
    __shared__ float ha[64][65];
    __shared__ float hb[64][65];
    const int t = threadIdx.x;
    const int base = blockIdx.x * 64;

    // stage rb tile: ha[m][0..7]
    for (int idx = t; idx < 512; idx += 256) {
        int m = idx >> 3, k = idx & 7;
        int e = base + m;
        ha[m][k] = (e < NE) ? rb[(size_t)e * 8 + k] : 0.f;
    }
    __syncthreads();

    const int ob = t & 15;
    const int mb = (t >> 4) * 4;

    // layer 1: K=8, scale 1/sqrt(8), silu : ha -> hb
    {
        float acc[4][4] = {};
#pragma unroll
        for (int k = 0; k < 8; ++k) {
            float wv[4];
#pragma unroll
            for (int c = 0; c < 4; ++c) wv[c] = w0[k * 64 + ob + 16 * c];
#pragma unroll
            for (int mm = 0; mm < 4; ++mm) {
                float hv = ha[mb + mm][k];
#pragma unroll
                for (int c = 0; c < 4; ++c) acc[mm][c] += hv * wv[c];
            }
        }
#pragma unroll
        for (int mm = 0; mm < 4; ++mm)
#pragma unroll
            for (int c = 0; c < 4; ++c)
                hb[mb + mm][ob + 16 * c] = silu_f(acc[mm][c] * 0.35355339059327373f);
    }
    __syncthreads();
    // layer 2: hb -> ha
    mlp_layer64<true>(hb, ha, w1, 0.125f, ob, mb);
    __syncthreads();
    // layer 3: ha -> hb
    mlp_layer64<true>(ha, hb, w2, 0.125f, ob, mb);
    __syncthreads();

    // layer 4: K=64, out 512, scale 0.125, no act, store bf16
    {
        const int o0 = t & 63;
        const int mB = (t >> 6) * 16;
        for (int rblk = 0; rblk < 2; ++rblk) {
            float acc[16][4] = {};
            for (int k = 0; k < 64; ++k) {
                float wv[4];
#pragma unroll
                for (int r = 0; r < 4; ++r) wv[r] = w3[k * 512 + o0 + 64 * (rblk * 4 + r)];
#pragma unroll
                for (int mm = 0; mm < 16; ++mm) {
                    float hv = hb[mB + mm][k];
#pragma unroll
                    for (int r = 0; r < 4; ++r) acc[mm][r] += hv * wv[r];
                }
            }
            for (int mm = 0; mm < 16; ++mm) {
                int e = base + mB + mm;
                if (e < NE) {
#pragma unroll
                    for (int r = 0; r < 4; ++r)
                        we[(size_t)e * 512 + o0 + 64 * (rblk * 4 + r)] =
                            __float2bfloat16(acc[mm][r] * 0.125f);
                }
            }
        }
    }
}

// ---------------- per-node gather + segment sum + W_post epilogue ----------------
__global__ __launch_bounds__(256) void k_gather(const float* __restrict__ x,
                                                const __hip_bfloat16* __restrict__ we,
                                                const float* __restrict__ sph,
                                                const int* __restrict__ ej,
                                                const int* __restrict__ offsets,
                                                const int* __restrict__ order,
                                                const float* __restrict__ Wpost,
                                                float* __restrict__ out) {
    __shared__ float tot[4 * 128 * 24];   // [wave][u][k], row stride 24 (16B-aligned float4 reads)
    const int t = threadIdx.x;
    const int w = t >> 6, lane = t & 63;
    const int n = blockIdx.x;
    const int s0 = offsets[n], s1 = offsets[n + 1];

    float acc0[16] = {};  // u = lane
    float acc1[16] = {};  // u = lane + 64

    const int PMAP[16] = {0,1,1,1, 2,2,2,2, 2,3,3,3, 3,3,3,3};

    for (int idx = s0 + w; idx < s1; idx += 4) {
        int e = order[idx];
        int j = ej[e];
        const float* xp = x + (size_t)j * 128;
        float xj0 = xp[lane];
        float xj1 = xp[lane + 64];
        const __hip_bfloat16* wep = we + (size_t)e * 512;
        float a0[4], a1[4];
#pragma unroll
        for (int p = 0; p < 4; ++p) {
            a0[p] = xj0 * __bfloat162float(wep[p * 128 + lane]);
            a1[p] = xj1 * __bfloat162float(wep[p * 128 + 64 + lane]);
        }
        const float4* Y4 = (const float4*)(sph + (size_t)e * 16);
        float yv[16];
        ((float4*)yv)[0] = Y4[0];
        ((float4*)yv)[1] = Y4[1];
        ((float4*)yv)[2] = Y4[2];
        ((float4*)yv)[3] = Y4[3];
#pragma unroll
        for (int k = 0; k < 16; ++k) {
            acc0[k] += a0[PMAP[k]] * yv[k];
            acc1[k] += a1[PMAP[k]] * yv[k];
        }
    }

    float* tw = tot + w * 3072;
#pragma unroll
    for (int k = 0; k < 16; ++k) {
        tw[lane * 24 + k]        = acc0[k];
        tw[(lane + 64) * 24 + k] = acc1[k];
    }
    __syncthreads();

    // reduce 4 wave-partials into tot[0..]
    for (int i = t; i < 2048; i += 256) {
        int u = i >> 4, k = i & 15;
        int a = u * 24 + k;
        tot[a] = tot[a] + tot[3072 + a] + tot[2 * 3072 + a] + tot[3 * 3072 + a];
    }
    __syncthreads();

    // out[n][v][k] = inv * sum_u W_post[p(k)][u][v] * tot[u][k]
    const int v = t & 127, kh = t >> 7;   // kh uniform per wave
    const float* W0 = Wpost + v;
    const float* W1 = Wpost + 16384 + v;
    const float* W2 = Wpost + 2 * 16384 + v;
    const float* W3 = Wpost + 3 * 16384 + v;
    float acc[8] = {};
    if (kh == 0) {
        for (int u = 0; u < 128; ++u) {
            float4 ta = *(const float4*)&tot[u * 24 + 0];
            float4 tb = *(const float4*)&tot[u * 24 + 4];
            float wa = W0[u * 128];
            float wb = W1[u * 128];
            float wc = W2[u * 128];
            acc[0] += wa * ta.x;
            acc[1] += wb * ta.y; acc[2] += wb * ta.z; acc[3] += wb * ta.w;
            acc[4] += wc * tb.x; acc[5] += wc * tb.y; acc[6] += wc * tb.z; acc[7] += wc * tb.w;
        }
    } else {
        for (int u = 0; u < 128; ++u) {
            float4 ta = *(const float4*)&tot[u * 24 + 8];
            float4 tb = *(const float4*)&tot[u * 24 + 12];
            float wc = W2[u * 128];
            float wd = W3[u * 128];
            acc[0] += wc * ta.x;
            acc[1] += wd * ta.y; acc[2] += wd * ta.z; acc[3] += wd * ta.w;
            acc[4] += wd * tb.x; acc[5] += wd * tb.y; acc[6] += wd * tb.z; acc[7] += wd * tb.w;
        }
    }
    float* op = out + (size_t)n * 2048 + v * 16 + kh * 8;
    const float inv = 0.08838834764831845f;
    float4 r0 = make_float4(acc[0] * inv, acc[1] * inv, acc[2] * inv, acc[3] * inv);
    float4 r1 = make_float4(acc[4] * inv, acc[5] * inv, acc[6] * inv, acc[7] * inv);
    *(float4*)op = r0;
    *(float4*)(op + 4) = r1;
}

// ---------------- launch ----------------
extern "C" void kernel_launch(void* const* d_in, const int* in_sizes, int n_in,
                              void* d_out, int out_size, void* d_ws, size_t ws_size,
                              hipStream_t stream) {
    const float* nf    = (const float*)d_in[0];
    const float* sph   = (const float*)d_in[1];
    const float* rb    = (const float*)d_in[2];
    const int*   ei    = (const int*)d_in[3];
    const int*   ej    = (const int*)d_in[4];
    const float* Wpre  = (const float*)d_in[5];
    const float* w0    = (const float*)d_in[6];
    const float* w1    = (const float*)d_in[7];
    const float* w2    = (const float*)d_in[8];
    const float* w3    = (const float*)d_in[9];
    const float* Wpost = (const float*)d_in[10];
    float* out = (float*)d_out;

    // workspace layout
    char* ws = (char*)d_ws;
    const size_t OFF_X       = 0;              // 5000*128*4     = 2,560,000
    const size_t OFF_WE      = 2560000;        // 100000*512*2   = 102,400,000
    const size_t OFF_COUNTS  = 104960000;      // 5000*4
    const size_t OFF_CURSOR  = 104980000;      // 5000*4
    const size_t OFF_OFFSETS = 105000000;      // 5001*4
    const size_t OFF_ORDER   = 105020032;      // 100000*4
    const size_t NEEDED      = 105420032;
    if (ws_size < NEEDED) return;  // fail loudly (output stays poisoned)

    float*          x       = (float*)(ws + OFF_X);
    __hip_bfloat16* we      = (__hip_bfloat16*)(ws + OFF_WE);
    int*            counts  = (int*)(ws + OFF_COUNTS);
    int*            cursor  = (int*)(ws + OFF_CURSOR);
    int*            offsets = (int*)(ws + OFF_OFFSETS);
    int*            order   = (int*)(ws + OFF_ORDER);

    hipMemsetAsync(ws + OFF_COUNTS, 0, 40000, stream);  // counts + cursor

    k_count<<<(NE + 255) / 256, 256, 0, stream>>>(ei, counts);
    k_scan<<<1, 256, 0, stream>>>(counts, offsets);
    k_fill<<<(NE + 255) / 256, 256, 0, stream>>>(ei, offsets, cursor, order);

    k_pre<<<NN, 128, 0, stream>>>(nf, Wpre, x);
    k_mlp<<<(NE + 63) / 64, 256, 0, stream>>>(rb, w0, w1, w2, w3, we);
    k_gather<<<NN, 256, 0, stream>>>(x, we, sph, ej, offsets, order, Wpost, out);
}

// Round 3
// 261.180 us; speedup vs baseline: 1.1636x; 1.1636x over previous
//
#include <hip/hip_runtime.h>
#include <hip/hip_bf16.h>

#define NN 5000
#define NE 100000

typedef unsigned short u16;
typedef __attribute__((ext_vector_type(8))) short bf16x8;
typedef __attribute__((ext_vector_type(4))) float f32x4;

__device__ __forceinline__ float silu_f(float x) {
    return x / (1.0f + __expf(-x));
}

// bf16 round-to-nearest-even split helpers
__device__ __forceinline__ u16 f2bf(float x) {
    unsigned int u = __float_as_uint(x);
    u += 0x7FFFu + ((u >> 16) & 1u);
    return (u16)(u >> 16);
}
__device__ __forceinline__ float bf2f(u16 h) {
    return __uint_as_float(((unsigned int)h) << 16);
}

// ---------------- x = nf @ W_pre * (1/sqrt(128)) ----------------
__global__ __launch_bounds__(128) void k_pre(const float* __restrict__ nf,
                                             const float* __restrict__ Wpre,
                                             float* __restrict__ x) {
    __shared__ float row[128];
    int n = blockIdx.x;
    int v = threadIdx.x;
    row[v] = nf[(size_t)n * 128 + v];
    __syncthreads();
    float acc = 0.f;
#pragma unroll 16
    for (int u = 0; u < 128; ++u) acc += row[u] * Wpre[u * 128 + v];
    x[(size_t)n * 128 + v] = acc * 0.08838834764831845f;
}

// ---------------- CSR build (int atomics only) ----------------
__global__ void k_count(const int* __restrict__ ei, int* __restrict__ counts) {
    int e = blockIdx.x * blockDim.x + threadIdx.x;
    if (e < NE) atomicAdd(&counts[ei[e]], 1);
}

__global__ __launch_bounds__(256) void k_scan(const int* __restrict__ counts,
                                              int* __restrict__ offsets) {
    __shared__ int part[256];
    int t = threadIdx.x;
    const int CH = 20;
    int lo = t * CH, hi = min(lo + CH, NN);
    int s = 0;
    for (int i = lo; i < hi; ++i) s += counts[i];
    part[t] = s;
    __syncthreads();
    if (t == 0) {
        int run = 0;
        for (int i = 0; i < 256; ++i) { int v = part[i]; part[i] = run; run += v; }
    }
    __syncthreads();
    int run = part[t];
    for (int i = lo; i < hi; ++i) { offsets[i] = run; run += counts[i]; }
    if (t == 0) offsets[NN] = NE;
}

__global__ void k_fill(const int* __restrict__ ei, const int* __restrict__ offsets,
                       int* __restrict__ cursor, int* __restrict__ order) {
    int e = blockIdx.x * blockDim.x + threadIdx.x;
    if (e < NE) {
        int i = ei[e];
        int pos = atomicAdd(&cursor[i], 1);
        order[offsets[i] + pos] = e;
    }
}

// ---------------- weight prep: transpose + bf16 hi/lo split ----------------
// wT[n][k] layout so B-fragments are contiguous 16B per lane.
__global__ __launch_bounds__(256) void k_wprep(const float* __restrict__ w1,
                                               const float* __restrict__ w2,
                                               const float* __restrict__ w3,
                                               u16* __restrict__ w1h, u16* __restrict__ w1l,
                                               u16* __restrict__ w2h, u16* __restrict__ w2l,
                                               u16* __restrict__ w3h, u16* __restrict__ w3l) {
    int i = blockIdx.x * 256 + threadIdx.x;
    if (i < 4096) {
        int k = i >> 6, n = i & 63;
        float v = w1[i];
        u16 h = f2bf(v), l = f2bf(v - bf2f(h));
        w1h[n * 64 + k] = h; w1l[n * 64 + k] = l;
        v = w2[i];
        h = f2bf(v); l = f2bf(v - bf2f(h));
        w2h[n * 64 + k] = h; w2l[n * 64 + k] = l;
    }
    if (i < 32768) {
        int k = i >> 9, n = i & 511;
        float v = w3[i];
        u16 h = f2bf(v), l = f2bf(v - bf2f(h));
        w3h[n * 64 + k] = h; w3l[n * 64 + k] = l;
    }
}

// ---------------- MFMA MLP layers ----------------
// LDS h tiles: [64 rows][64 cols] bf16, byte offset = row*128 + col*2,
// XOR-swizzled with ((row&7)<<4) to kill ds_read_b128 bank conflicts.

// 64->64 layer with silu; each wave owns 16 output cols, all 64 rows.
__device__ __forceinline__ void layer_mid(const char* sh, const char* sl,
                                          const u16* __restrict__ wh,
                                          const u16* __restrict__ wl,
                                          char* dh, char* dl, int w, int l) {
    const int col = w * 16 + (l & 15);
    bf16x8 B[2][2];
#pragma unroll
    for (int kc = 0; kc < 2; ++kc) {
        B[kc][0] = *(const bf16x8*)(wh + col * 64 + kc * 32 + ((l >> 4) << 3));
        B[kc][1] = *(const bf16x8*)(wl + col * 64 + kc * 32 + ((l >> 4) << 3));
    }
#pragma unroll
    for (int rt = 0; rt < 4; ++rt) {
        const int arow = rt * 16 + (l & 15);
        f32x4 acc = {0.f, 0.f, 0.f, 0.f};
#pragma unroll
        for (int kc = 0; kc < 2; ++kc) {
            int off = (arow * 128 + kc * 64 + ((l >> 4) << 4)) ^ ((arow & 7) << 4);
            bf16x8 ah = *(const bf16x8*)(sh + off);
            bf16x8 al = *(const bf16x8*)(sl + off);
            acc = __builtin_amdgcn_mfma_f32_16x16x32_bf16(ah, B[kc][0], acc, 0, 0, 0);
            acc = __builtin_amdgcn_mfma_f32_16x16x32_bf16(ah, B[kc][1], acc, 0, 0, 0);
            acc = __builtin_amdgcn_mfma_f32_16x16x32_bf16(al, B[kc][0], acc, 0, 0, 0);
        }
#pragma unroll
        for (int r = 0; r < 4; ++r) {
            float v = silu_f(acc[r] * 0.125f);
            u16 hi = f2bf(v), lo = f2bf(v - bf2f(hi));
            int orow = rt * 16 + ((l >> 4) << 2) + r;
            int off = (orow * 128 + col * 2) ^ ((orow & 7) << 4);
            *(u16*)(dh + off) = hi;
            *(u16*)(dl + off) = lo;
        }
    }
}

// 64->512 output layer, no act, store bf16 to global.
// Wave w owns rows (w&1)*32..+32, cols (w>>1)*256..+256.
__device__ __forceinline__ void layer_out(const char* sh, const char* sl,
                                          const u16* __restrict__ wh,
                                          const u16* __restrict__ wl,
                                          u16* __restrict__ we, int base, int w, int l) {
    const int r0 = (w & 1) * 32;
    const int c0 = (w >> 1) * 256;
    bf16x8 A[2][2][2];  // [rt][kc][hi/lo]
#pragma unroll
    for (int rt = 0; rt < 2; ++rt)
#pragma unroll
        for (int kc = 0; kc < 2; ++kc) {
            int row = r0 + rt * 16 + (l & 15);
            int off = (row * 128 + kc * 64 + ((l >> 4) << 4)) ^ ((row & 7) << 4);
            A[rt][kc][0] = *(const bf16x8*)(sh + off);
            A[rt][kc][1] = *(const bf16x8*)(sl + off);
        }
    for (int nt = 0; nt < 16; ++nt) {
        const int col = c0 + nt * 16 + (l & 15);
        f32x4 acc[2] = {{0.f, 0.f, 0.f, 0.f}, {0.f, 0.f, 0.f, 0.f}};
#pragma unroll
        for (int kc = 0; kc < 2; ++kc) {
            bf16x8 bh = *(const bf16x8*)(wh + col * 64 + kc * 32 + ((l >> 4) << 3));
            bf16x8 bl = *(const bf16x8*)(wl + col * 64 + kc * 32 + ((l >> 4) << 3));
#pragma unroll
            for (int rt = 0; rt < 2; ++rt) {
                acc[rt] = __builtin_amdgcn_mfma_f32_16x16x32_bf16(A[rt][kc][0], bh, acc[rt], 0, 0, 0);
                acc[rt] = __builtin_amdgcn_mfma_f32_16x16x32_bf16(A[rt][kc][0], bl, acc[rt], 0, 0, 0);
                acc[rt] = __builtin_amdgcn_mfma_f32_16x16x32_bf16(A[rt][kc][1], bh, acc[rt], 0, 0, 0);
            }
        }
#pragma unroll
        for (int rt = 0; rt < 2; ++rt)
#pragma unroll
            for (int r = 0; r < 4; ++r) {
                int row = r0 + rt * 16 + ((l >> 4) << 2) + r;
                int e = base + row;
                if (e < NE) we[(size_t)e * 512 + col] = f2bf(acc[rt][r] * 0.125f);
            }
    }
}

__global__ __launch_bounds__(256) void k_mlp(const float* __restrict__ rb,
                                             const float* __restrict__ w0,
                                             const u16* __restrict__ w1h, const u16* __restrict__ w1l,
                                             const u16* __restrict__ w2h, const u16* __restrict__ w2l,
                                             const u16* __restrict__ w3h, const u16* __restrict__ w3l,
                                             u16* __restrict__ we) {
    __shared__ __align__(16) char hAh[8192];
    __shared__ __align__(16) char hAl[8192];
    __shared__ __align__(16) char hBh[8192];
    __shared__ __align__(16) char hBl[8192];
    __shared__ float rbs[512];
    const int t = threadIdx.x;
    const int l = t & 63, w = t >> 6;
    const int base = blockIdx.x * 64;

    for (int i = t; i < 512; i += 256) {
        int e = base + (i >> 3);
        rbs[i] = (e < NE) ? rb[(size_t)e * 8 + (i & 7)] : 0.f;
    }
    __syncthreads();

    // layer 1 (K=8) scalar f32, output split to bf16 hi/lo in LDS
    {
        const int m = t >> 2, n0 = (t & 3) * 16;
        float h[16];
#pragma unroll
        for (int nn = 0; nn < 16; ++nn) h[nn] = 0.f;
#pragma unroll
        for (int k = 0; k < 8; ++k) {
            float r = rbs[m * 8 + k];
            const float* wp = w0 + k * 64 + n0;
#pragma unroll
            for (int nn = 0; nn < 16; ++nn) h[nn] += r * wp[nn];
        }
#pragma unroll
        for (int nn = 0; nn < 16; ++nn) {
            float v = silu_f(h[nn] * 0.35355339059327373f);
            u16 hi = f2bf(v), lo = f2bf(v - bf2f(hi));
            int off = (m * 128 + (n0 + nn) * 2) ^ ((m & 7) << 4);
            *(u16*)(hAh + off) = hi;
            *(u16*)(hAl + off) = lo;
        }
    }
    __syncthreads();
    layer_mid(hAh, hAl, w1h, w1l, hBh, hBl, w, l);
    __syncthreads();
    layer_mid(hBh, hBl, w2h, w2l, hAh, hAl, w, l);
    __syncthreads();
    layer_out(hAh, hAl, w3h, w3l, we, base, w, l);
}

// ---------------- per-node gather + segment sum + W_post epilogue ----------------
__global__ __launch_bounds__(256) void k_gather(const float* __restrict__ x,
                                                const u16* __restrict__ we,
                                                const float* __restrict__ sph,
                                                const int* __restrict__ ej,
                                                const int* __restrict__ offsets,
                                                const int* __restrict__ order,
                                                const float* __restrict__ Wpost,
                                                float* __restrict__ out) {
    __shared__ float tot[4 * 128 * 24];
    const int t = threadIdx.x;
    const int w = t >> 6, lane = t & 63;
    const int n = blockIdx.x;
    const int s0 = offsets[n], s1 = offsets[n + 1];

    float acc0[16] = {};
    float acc1[16] = {};

    const int PMAP[16] = {0,1,1,1, 2,2,2,2, 2,3,3,3, 3,3,3,3};

    for (int idx = s0 + w; idx < s1; idx += 4) {
        int e = order[idx];
        int j = ej[e];
        const float* xp = x + (size_t)j * 128;
        float xj0 = xp[lane];
        float xj1 = xp[lane + 64];
        const u16* wep = we + (size_t)e * 512;
        float a0[4], a1[4];
#pragma unroll
        for (int p = 0; p < 4; ++p) {
            a0[p] = xj0 * bf2f(wep[p * 128 + lane]);
            a1[p] = xj1 * bf2f(wep[p * 128 + 64 + lane]);
        }
        const float4* Y4 = (const float4*)(sph + (size_t)e * 16);
        float yv[16];
        ((float4*)yv)[0] = Y4[0];
        ((float4*)yv)[1] = Y4[1];
        ((float4*)yv)[2] = Y4[2];
        ((float4*)yv)[3] = Y4[3];
#pragma unroll
        for (int k = 0; k < 16; ++k) {
            acc0[k] += a0[PMAP[k]] * yv[k];
            acc1[k] += a1[PMAP[k]] * yv[k];
        }
    }

    float* tw = tot + w * 3072;
#pragma unroll
    for (int k = 0; k < 16; ++k) {
        tw[lane * 24 + k]        = acc0[k];
        tw[(lane + 64) * 24 + k] = acc1[k];
    }
    __syncthreads();

    for (int i = t; i < 2048; i += 256) {
        int u = i >> 4, k = i & 15;
        int a = u * 24 + k;
        tot[a] = tot[a] + tot[3072 + a] + tot[2 * 3072 + a] + tot[3 * 3072 + a];
    }
    __syncthreads();

    const int v = t & 127, kh = t >> 7;
    const float* W0 = Wpost + v;
    const float* W1 = Wpost + 16384 + v;
    const float* W2 = Wpost + 2 * 16384 + v;
    const float* W3 = Wpost + 3 * 16384 + v;
    float acc[8] = {};
    if (kh == 0) {
        for (int u = 0; u < 128; ++u) {
            float4 ta = *(const float4*)&tot[u * 24 + 0];
            float4 tb = *(const float4*)&tot[u * 24 + 4];
            float wa = W0[u * 128];
            float wb = W1[u * 128];
            float wc = W2[u * 128];
            acc[0] += wa * ta.x;
            acc[1] += wb * ta.y; acc[2] += wb * ta.z; acc[3] += wb * ta.w;
            acc[4] += wc * tb.x; acc[5] += wc * tb.y; acc[6] += wc * tb.z; acc[7] += wc * tb.w;
        }
    } else {
        for (int u = 0; u < 128; ++u) {
            float4 ta = *(const float4*)&tot[u * 24 + 8];
            float4 tb = *(const float4*)&tot[u * 24 + 12];
            float wc = W2[u * 128];
            float wd = W3[u * 128];
            acc[0] += wc * ta.x;
            acc[1] += wd * ta.y; acc[2] += wd * ta.z; acc[3] += wd * ta.w;
            acc[4] += wd * tb.x; acc[5] += wd * tb.y; acc[6] += wd * tb.z; acc[7] += wd * tb.w;
        }
    }
    float* op = out + (size_t)n * 2048 + v * 16 + kh * 8;
    const float inv = 0.08838834764831845f;
    float4 r0 = make_float4(acc[0] * inv, acc[1] * inv, acc[2] * inv, acc[3] * inv);
    float4 r1 = make_float4(acc[4] * inv, acc[5] * inv, acc[6] * inv, acc[7] * inv);
    *(float4*)op = r0;
    *(float4*)(op + 4) = r1;
}

// ---------------- launch ----------------
extern "C" void kernel_launch(void* const* d_in, const int* in_sizes, int n_in,
                              void* d_out, int out_size, void* d_ws, size_t ws_size,
                              hipStream_t stream) {
    const float* nf    = (const float*)d_in[0];
    const float* sph   = (const float*)d_in[1];
    const float* rb    = (const float*)d_in[2];
    const int*   ei    = (const int*)d_in[3];
    const int*   ej    = (const int*)d_in[4];
    const float* Wpre  = (const float*)d_in[5];
    const float* w0    = (const float*)d_in[6];
    const float* w1    = (const float*)d_in[7];
    const float* w2    = (const float*)d_in[8];
    const float* w3    = (const float*)d_in[9];
    const float* Wpost = (const float*)d_in[10];
    float* out = (float*)d_out;

    char* ws = (char*)d_ws;
    const size_t OFF_X       = 0;              // 2,560,000
    const size_t OFF_WE      = 2560000;        // 102,400,000 (bf16)
    const size_t OFF_COUNTS  = 104960000;
    const size_t OFF_CURSOR  = 104980000;
    const size_t OFF_OFFSETS = 105000000;
    const size_t OFF_ORDER   = 105020032;      // 400,000
    const size_t OFF_W1H     = 105420032;      // 8 KB each
    const size_t OFF_W1L     = OFF_W1H + 8192;
    const size_t OFF_W2H     = OFF_W1L + 8192;
    const size_t OFF_W2L     = OFF_W2H + 8192;
    const size_t OFF_W3H     = OFF_W2L + 8192; // 64 KB each
    const size_t OFF_W3L     = OFF_W3H + 65536;
    const size_t NEEDED      = OFF_W3L + 65536;
    if (ws_size < NEEDED) return;

    float* x       = (float*)(ws + OFF_X);
    u16*   we      = (u16*)(ws + OFF_WE);
    int*   counts  = (int*)(ws + OFF_COUNTS);
    int*   cursor  = (int*)(ws + OFF_CURSOR);
    int*   offsets = (int*)(ws + OFF_OFFSETS);
    int*   order   = (int*)(ws + OFF_ORDER);
    u16*   w1h = (u16*)(ws + OFF_W1H); u16* w1l = (u16*)(ws + OFF_W1L);
    u16*   w2h = (u16*)(ws + OFF_W2H); u16* w2l = (u16*)(ws + OFF_W2L);
    u16*   w3h = (u16*)(ws + OFF_W3H); u16* w3l = (u16*)(ws + OFF_W3L);

    (void)hipMemsetAsync(ws + OFF_COUNTS, 0, 40000, stream);

    k_count<<<(NE + 255) / 256, 256, 0, stream>>>(ei, counts);
    k_scan<<<1, 256, 0, stream>>>(counts, offsets);
    k_fill<<<(NE + 255) / 256, 256, 0, stream>>>(ei, offsets, cursor, order);
    k_wprep<<<128, 256, 0, stream>>>(w1, w2, w3, w1h, w1l, w2h, w2l, w3h, w3l);

    k_pre<<<NN, 128, 0, stream>>>(nf, Wpre, x);
    k_mlp<<<(NE + 63) / 64, 256, 0, stream>>>(rb, w0, w1h, w1l, w2h, w2l, w3h, w3l, we);
    k_gather<<<NN, 256, 0, stream>>>(x, we, sph, ej, offsets, order, Wpost, out);
}